// Round 23
// baseline (70.434 us; speedup 1.0000x reference)
//
#include <hip/hip_runtime.h>
#include <hip/hip_bf16.h>

#define NN 50000
#define EE 800000
#define DD 64
#define NB32 1563                  // ceil(NN / 32): 32-node bins
#define PA_BLOCKS 256
#define PA_CHUNK (EE / PA_BLOCKS)  // 3125
#define CAP32 768                  // capacity per 32-node bin (mean 512, 11 sigma)
#define CVT_XBLOCKS 3125
#define FRONT_BLOCKS (CVT_XBLOCKS + 8 + 1)

typedef short bf16x8 __attribute__((ext_vector_type(8)));   // 8 bf16 = 4 VGPR
typedef float f32x4 __attribute__((ext_vector_type(4)));

__device__ inline unsigned short f2bf(float f) {          // RNE float->bf16
    unsigned u = __float_as_uint(f);
    return (unsigned short)((u + 0x7FFF + ((u >> 16) & 1)) >> 16);
}
__device__ inline float bflo(unsigned u) { return __uint_as_float(u << 16); }
__device__ inline float bfhi(unsigned u) { return __uint_as_float(u & 0xFFFF0000u); }
__device__ inline unsigned bfpack(float a, float b) {     // mem order: [a, b]
    return (unsigned)f2bf(a) | ((unsigned)f2bf(b) << 16);
}

// ------- front: bf16 mirror of x, TRANSPOSED bf16 W (k-contiguous), cursors -
__global__ void front_kernel(const float* __restrict__ x,
                             const float* __restrict__ Wl1,
                             const float* __restrict__ Wr1,
                             const float* __restrict__ Wl2,
                             const float* __restrict__ Wr2,
                             unsigned short* __restrict__ xbf,
                             unsigned short* __restrict__ wbf_t,
                             int* __restrict__ binCursor) {
    const int tid = threadIdx.x;
    const int bid = blockIdx.x;
    if (bid < CVT_XBLOCKS) {
        int i = bid * 256 + tid;                  // float4 chunk of x
        if (i < NN * DD / 4) {
            float4 v = reinterpret_cast<const float4*>(x)[i];
            ushort4 u;
            u.x = f2bf(v.x); u.y = f2bf(v.y); u.z = f2bf(v.z); u.w = f2bf(v.w);
            reinterpret_cast<ushort4*>(xbf)[i] = u;
        }
    } else if (bid < CVT_XBLOCKS + 8) {
        // wbf_t[layer][col][k]: k<64 -> Wl[k][col], k>=64 -> Wr[k-64][col]
        int j = (bid - CVT_XBLOCKS) * 256 + tid;  // 0..2047 (uint4 index)
        int m   = j >> 10;                        // layer
        int col = (j >> 4) & 63;
        int kg  = j & 15;                         // k-group of 8
        const float* WlX = m ? Wl2 : Wl1;
        const float* WrX = m ? Wr2 : Wr1;
        unsigned short t8[8];
        #pragma unroll
        for (int t = 0; t < 8; ++t) {
            int k = kg * 8 + t;
            float v = (k < 64) ? WlX[k * 64 + col] : WrX[(k - 64) * 64 + col];
            t8[t] = f2bf(v);
        }
        uint4 u;
        u.x = (unsigned)t8[0] | ((unsigned)t8[1] << 16);
        u.y = (unsigned)t8[2] | ((unsigned)t8[3] << 16);
        u.z = (unsigned)t8[4] | ((unsigned)t8[5] << 16);
        u.w = (unsigned)t8[6] | ((unsigned)t8[7] << 16);
        reinterpret_cast<uint4*>(wbf_t)[j] = u;
    } else {
        for (int i = tid; i < NB32; i += 256) binCursor[i] = i * CAP32;
    }
}

// ------- scatter edges into fixed-capacity 32-node bin slots ---------------
// dst chunk staged once into LDS (read twice before: hist + placement).
__global__ void binscatter_kernel(const int* __restrict__ src, const int* __restrict__ dst,
                                  int* __restrict__ binCursor, unsigned* __restrict__ ebuf) {
    __shared__ int hist[NB32];
    __shared__ int base[NB32];
    __shared__ int dloc[PA_CHUNK];     // 12.5KB
    const int tid = threadIdx.x;
    const int e0 = blockIdx.x * PA_CHUNK;
    for (int i = tid; i < NB32; i += 256) hist[i] = 0;
    for (int i = tid; i < PA_CHUNK; i += 256) dloc[i] = dst[e0 + i];
    __syncthreads();
    for (int i = tid; i < PA_CHUNK; i += 256)
        atomicAdd(&hist[dloc[i] >> 5], 1);
    __syncthreads();
    for (int i = tid; i < NB32; i += 256) {
        int c = hist[i];
        base[i] = c ? atomicAdd(&binCursor[i], c) : 0;
        hist[i] = 0;               // reuse as local cursor
    }
    __syncthreads();
    for (int i = tid; i < PA_CHUNK; i += 256) {
        int d = dloc[i];
        int b = d >> 5;
        int off = atomicAdd(&hist[b], 1);
        ebuf[base[b] + off] = ((unsigned)(d & 31) << 16) | (unsigned)src[e0 + i];
    }
}

// ------- fused layer: [sort] + balanced gather -> bf16 A + MFMA GEMM -------
// One block per 32-node bin. Degree-descending perm assigns nodes to threads
// so each wave's 8 nodes have near-equal trip counts (kills max-of-8 skew).
__launch_bounds__(256, 5)
__global__ void fused_layer_kernel(const unsigned* __restrict__ ebuf,
                                   const int* __restrict__ binCursor,
                                   unsigned short* __restrict__ esrc,
                                   int* __restrict__ offs,
                                   const unsigned short* __restrict__ feat,
                                   const unsigned short* __restrict__ selfb,
                                   const unsigned short* __restrict__ Wbf, // [64][128] bf16
                                   const float* __restrict__ bias,
                                   float* __restrict__ outp,
                                   unsigned short* __restrict__ outbf,
                                   int relu, int sortMode) {
    __shared__ unsigned short eidx[CAP32];
    __shared__ int h32[32];
    __shared__ int loff[33];
    __shared__ unsigned char perm[32];
    __shared__ unsigned short Albs[32 * 128];   // 8KB  bf16 A tile
    __shared__ unsigned short Wlds[64 * 128];   // 16KB bf16 Wt; pre-stage: sort scratch
    const int tid = threadIdx.x;
    const int g = blockIdx.x;
    const int nbase = g * 32;
    const int e0 = g * CAP32;
    const int cnt = binCursor[g] - e0;
    char* Ab = reinterpret_cast<char*>(Albs);
    char* Wb = reinterpret_cast<char*>(Wlds);

    if (sortMode) {
        unsigned* scratch = reinterpret_cast<unsigned*>(Wlds);   // 4096 u32 >= CAP32
        for (int i = tid; i < cnt; i += 256) scratch[i] = ebuf[e0 + i];
        if (tid < 32) h32[tid] = 0;
        __syncthreads();
        for (int i = tid; i < cnt; i += 256)
            atomicAdd(&h32[(scratch[i] >> 16) & 31], 1);
        __syncthreads();
        if (tid == 0) {
            int run = 0;
            #pragma unroll
            for (int i = 0; i < 32; ++i) { loff[i] = run; run += h32[i]; }
            loff[32] = run;        // == cnt
        }
        __syncthreads();
        if (tid < 32) {
            offs[nbase + tid] = e0 + loff[tid];
            h32[tid] = loff[tid];  // reuse as cursor
        }
        // degree-descending rank permutation (loff final here)
        if (tid >= 64 && tid < 96) {
            int i = tid - 64;
            int deg = loff[i + 1] - loff[i];
            int r = 0;
            #pragma unroll 8
            for (int j = 0; j < 32; ++j) {
                int dj = loff[j + 1] - loff[j];
                r += (dj > deg) || (dj == deg && j < i);
            }
            perm[r] = (unsigned char)i;
        }
        __syncthreads();
        for (int i = tid; i < cnt; i += 256) {
            unsigned p = scratch[i];
            int n = (p >> 16) & 31;
            int pos = atomicAdd(&h32[n], 1);
            eidx[pos] = (unsigned short)(p & 0xFFFFu);
        }
        __syncthreads();           // scratch reads done; Wlds now reusable
        for (int i = tid; i < cnt; i += 256) esrc[e0 + i] = eidx[i];
    } else {
        if (tid < 32) loff[tid] = offs[nbase + tid] - e0;
        if (tid == 0) loff[32] = cnt;
        __syncthreads();
        for (int i = tid; i < cnt; i += 256) eidx[i] = esrc[e0 + i];
        if (tid >= 64 && tid < 96) {
            int i = tid - 64;
            int deg = loff[i + 1] - loff[i];
            int r = 0;
            #pragma unroll 8
            for (int j = 0; j < 32; ++j) {
                int dj = loff[j + 1] - loff[j];
                r += (dj > deg) || (dj == deg && j < i);
            }
            perm[r] = (unsigned char)i;
        }
        __syncthreads();
    }

    // ---- stage Wt into LDS (swizzled) [overlaps gather issue] ----
    #pragma unroll
    for (int i = 0; i < 4; ++i) {
        int idx = i * 256 + tid;            // 0..1023 uint4; col=idx>>4, kg=idx&15
        uint4 u = reinterpret_cast<const uint4*>(Wbf)[idx];
        int col = idx >> 4, kg = idx & 15;
        int byte = (col * 256 + kg * 16) ^ ((col & 7) << 4);
        *reinterpret_cast<uint4*>(Wb + byte) = u;
    }
    // ---- stage self rows into A[k=64..127] (straight bf16 copy) ----
    {
        int n  = tid >> 3;                  // 0..31
        int kq = tid & 7;                   // k-group 8..15
        int node = nbase + n;
        uint4 u = make_uint4(0u, 0u, 0u, 0u);
        if (node < NN)
            u = *reinterpret_cast<const uint4*>(selfb + (size_t)node * DD + kq * 8);
        int byte = (n * 256 + (8 + kq) * 16) ^ ((n & 7) << 4);
        *reinterpret_cast<uint4*>(Ab + byte) = u;
    }

    // ---- gather: 8 lanes/node, degree-balanced node assignment ----
    {
        const int nl = perm[tid >> 3];      // balanced local node
        const int q  = tid & 7;             // k-group 0..7 (elems q*8..q*8+7)
        const int qo = q << 3;
        const int le0 = loff[nl], le1 = loff[nl + 1];
        float a0 = 0.f, a1 = 0.f, a2 = 0.f, a3 = 0.f;
        float a4 = 0.f, a5 = 0.f, a6 = 0.f, a7 = 0.f;
        int e = le0;
        for (; e + 7 < le1; e += 8) {
            uint4 u0 = *reinterpret_cast<const uint4*>(feat + (size_t)eidx[e + 0] * DD + qo);
            uint4 u1 = *reinterpret_cast<const uint4*>(feat + (size_t)eidx[e + 1] * DD + qo);
            uint4 u2 = *reinterpret_cast<const uint4*>(feat + (size_t)eidx[e + 2] * DD + qo);
            uint4 u3 = *reinterpret_cast<const uint4*>(feat + (size_t)eidx[e + 3] * DD + qo);
            uint4 u4 = *reinterpret_cast<const uint4*>(feat + (size_t)eidx[e + 4] * DD + qo);
            uint4 u5 = *reinterpret_cast<const uint4*>(feat + (size_t)eidx[e + 5] * DD + qo);
            uint4 u6 = *reinterpret_cast<const uint4*>(feat + (size_t)eidx[e + 6] * DD + qo);
            uint4 u7 = *reinterpret_cast<const uint4*>(feat + (size_t)eidx[e + 7] * DD + qo);
            a0 += ((bflo(u0.x) + bflo(u1.x)) + (bflo(u2.x) + bflo(u3.x)))
                + ((bflo(u4.x) + bflo(u5.x)) + (bflo(u6.x) + bflo(u7.x)));
            a1 += ((bfhi(u0.x) + bfhi(u1.x)) + (bfhi(u2.x) + bfhi(u3.x)))
                + ((bfhi(u4.x) + bfhi(u5.x)) + (bfhi(u6.x) + bfhi(u7.x)));
            a2 += ((bflo(u0.y) + bflo(u1.y)) + (bflo(u2.y) + bflo(u3.y)))
                + ((bflo(u4.y) + bflo(u5.y)) + (bflo(u6.y) + bflo(u7.y)));
            a3 += ((bfhi(u0.y) + bfhi(u1.y)) + (bfhi(u2.y) + bfhi(u3.y)))
                + ((bfhi(u4.y) + bfhi(u5.y)) + (bfhi(u6.y) + bfhi(u7.y)));
            a4 += ((bflo(u0.z) + bflo(u1.z)) + (bflo(u2.z) + bflo(u3.z)))
                + ((bflo(u4.z) + bflo(u5.z)) + (bflo(u6.z) + bflo(u7.z)));
            a5 += ((bfhi(u0.z) + bfhi(u1.z)) + (bfhi(u2.z) + bfhi(u3.z)))
                + ((bfhi(u4.z) + bfhi(u5.z)) + (bfhi(u6.z) + bfhi(u7.z)));
            a6 += ((bflo(u0.w) + bflo(u1.w)) + (bflo(u2.w) + bflo(u3.w)))
                + ((bflo(u4.w) + bflo(u5.w)) + (bflo(u6.w) + bflo(u7.w)));
            a7 += ((bfhi(u0.w) + bfhi(u1.w)) + (bfhi(u2.w) + bfhi(u3.w)))
                + ((bfhi(u4.w) + bfhi(u5.w)) + (bfhi(u6.w) + bfhi(u7.w)));
        }
        for (; e + 1 < le1; e += 2) {
            uint4 u0 = *reinterpret_cast<const uint4*>(feat + (size_t)eidx[e + 0] * DD + qo);
            uint4 u1 = *reinterpret_cast<const uint4*>(feat + (size_t)eidx[e + 1] * DD + qo);
            a0 += bflo(u0.x) + bflo(u1.x); a1 += bfhi(u0.x) + bfhi(u1.x);
            a2 += bflo(u0.y) + bflo(u1.y); a3 += bfhi(u0.y) + bfhi(u1.y);
            a4 += bflo(u0.z) + bflo(u1.z); a5 += bfhi(u0.z) + bfhi(u1.z);
            a6 += bflo(u0.w) + bflo(u1.w); a7 += bfhi(u0.w) + bfhi(u1.w);
        }
        if (e < le1) {
            uint4 u0 = *reinterpret_cast<const uint4*>(feat + (size_t)eidx[e] * DD + qo);
            a0 += bflo(u0.x); a1 += bfhi(u0.x);
            a2 += bflo(u0.y); a3 += bfhi(u0.y);
            a4 += bflo(u0.z); a5 += bfhi(u0.z);
            a6 += bflo(u0.w); a7 += bfhi(u0.w);
        }
        float iv = (le1 > le0) ? (1.0f / (float)(le1 - le0)) : 0.0f;
        uint4 pk;
        pk.x = bfpack(a0 * iv, a1 * iv);
        pk.y = bfpack(a2 * iv, a3 * iv);
        pk.z = bfpack(a4 * iv, a5 * iv);
        pk.w = bfpack(a6 * iv, a7 * iv);
        int byte = (nl * 256 + q * 16) ^ ((nl & 7) << 4);
        *reinterpret_cast<uint4*>(Ab + byte) = pk;
    }
    __syncthreads();

    // ---- MFMA GEMM: out[32][64] = A[32][128] @ Wt^T + bias ----
    {
        const int lane = tid & 63;
        const int w = tid >> 6;             // wave 0..3
        const int mt = w & 1;               // M-tile (rows mt*16..+15)
        const int nt0 = (w >> 1) * 2;       // first N-tile
        const int lr = lane & 15;           // A-row / B-col within tile
        const int lg = lane >> 4;           // k-subgroup 0..3

        const int arow = mt * 16 + lr;
        const int c0 = nt0 * 16 + lr;
        const int c1 = c0 + 16;
        f32x4 acc0, acc1;
        {
            float b0 = bias[c0], b1 = bias[c1];
            #pragma unroll
            for (int r = 0; r < 4; ++r) { acc0[r] = b0; acc1[r] = b1; }
        }
        const int aswz = (arow & 7) << 4;
        const int b0swz = (c0 & 7) << 4;
        const int b1swz = (c1 & 7) << 4;
        #pragma unroll
        for (int ks = 0; ks < 4; ++ks) {
            int kg = ks * 4 + lg;           // k-group of 8 (k = kg*8)
            bf16x8 a = *reinterpret_cast<const bf16x8*>(
                Ab + ((arow * 256 + kg * 16) ^ aswz));
            bf16x8 b0 = *reinterpret_cast<const bf16x8*>(
                Wb + ((c0 * 256 + kg * 16) ^ b0swz));
            bf16x8 b1 = *reinterpret_cast<const bf16x8*>(
                Wb + ((c1 * 256 + kg * 16) ^ b1swz));
            acc0 = __builtin_amdgcn_mfma_f32_16x16x32_bf16(a, b0, acc0, 0, 0, 0);
            acc1 = __builtin_amdgcn_mfma_f32_16x16x32_bf16(a, b1, acc1, 0, 0, 0);
        }
        // epilogue: row = lg*4 + r (verified C/D mapping), col = lr
        #pragma unroll
        for (int r = 0; r < 4; ++r) {
            int node = nbase + mt * 16 + lg * 4 + r;
            if (node < NN) {
                float v0 = acc0[r], v1 = acc1[r];
                if (relu) { v0 = fmaxf(v0, 0.f); v1 = fmaxf(v1, 0.f); }
                if (outp) {
                    outp[(size_t)node * DD + c0] = v0;
                    outp[(size_t)node * DD + c1] = v1;
                }
                if (outbf) {
                    outbf[(size_t)node * DD + c0] = f2bf(v0);
                    outbf[(size_t)node * DD + c1] = f2bf(v1);
                }
            }
        }
    }
}

static inline size_t rup(size_t b) { return (b + 255) & ~(size_t)255; }

extern "C" void kernel_launch(void* const* d_in, const int* in_sizes, int n_in,
                              void* d_out, int out_size, void* d_ws, size_t ws_size,
                              hipStream_t stream) {
    const float* x   = (const float*)d_in[0];
    const int*   ei  = (const int*)d_in[1];
    const float* Wl1 = (const float*)d_in[2];
    const float* Wr1 = (const float*)d_in[3];
    const float* b1  = (const float*)d_in[4];
    const float* Wl2 = (const float*)d_in[5];
    const float* Wr2 = (const float*)d_in[6];
    const float* b2  = (const float*)d_in[7];
    float* out = (float*)d_out;

    const int* src = ei;        // edge_index[0]
    const int* dst = ei + EE;   // edge_index[1]

    // workspace layout (256B-aligned regions), ~14 MB
    char* p = (char*)d_ws;
    int* binCursor        = (int*)p;            p += rup((size_t)NB32 * 4);
    unsigned* ebuf        = (unsigned*)p;       p += rup((size_t)NB32 * CAP32 * 4);
    unsigned short* esrc  = (unsigned short*)p; p += rup((size_t)NB32 * CAP32 * 2);
    int* offs             = (int*)p;            p += rup((size_t)NB32 * 32 * 4);
    unsigned short* xbf   = (unsigned short*)p; p += rup((size_t)NN * DD * 2);
    unsigned short* hbf   = (unsigned short*)p; p += rup((size_t)NN * DD * 2);
    unsigned short* wbf_t = (unsigned short*)p; p += rup((size_t)2 * 64 * 128 * 2);

    // 4 launches total
    front_kernel<<<FRONT_BLOCKS, 256, 0, stream>>>(x, Wl1, Wr1, Wl2, Wr2,
                                                   xbf, wbf_t, binCursor);
    binscatter_kernel<<<PA_BLOCKS, 256, 0, stream>>>(src, dst, binCursor, ebuf);

    // layer 1: local sort + balanced gather(xbf) + MFMA GEMM -> hbf
    fused_layer_kernel<<<NB32, 256, 0, stream>>>(ebuf, binCursor, esrc, offs,
                                                 xbf, xbf, wbf_t, b1,
                                                 nullptr, hbf, 1, 1);
    // layer 2: balanced gather(hbf) + MFMA GEMM -> out
    fused_layer_kernel<<<NB32, 256, 0, stream>>>(ebuf, binCursor, esrc, offs,
                                                 hbf, hbf, wbf_t + 8192, b2,
                                                 out, nullptr, 0, 0);
}

// Round 24
// 70.224 us; speedup vs baseline: 1.0030x; 1.0030x over previous
//
#include <hip/hip_runtime.h>
#include <hip/hip_bf16.h>

#define NN 50000
#define EE 800000
#define DD 64
#define NB32 1563                  // ceil(NN / 32): 32-node bins
#define PA_BLOCKS 256
#define PA_CHUNK (EE / PA_BLOCKS)  // 3125
#define CAP32 768                  // capacity per 32-node bin (mean 512, 11 sigma)
#define CVT_XBLOCKS 3125
#define FRONT_BLOCKS (CVT_XBLOCKS + 8 + 1)

typedef short bf16x8 __attribute__((ext_vector_type(8)));   // 8 bf16 = 4 VGPR
typedef float f32x4 __attribute__((ext_vector_type(4)));

__device__ inline unsigned short f2bf(float f) {          // RNE float->bf16
    unsigned u = __float_as_uint(f);
    return (unsigned short)((u + 0x7FFF + ((u >> 16) & 1)) >> 16);
}
__device__ inline float bflo(unsigned u) { return __uint_as_float(u << 16); }
__device__ inline float bfhi(unsigned u) { return __uint_as_float(u & 0xFFFF0000u); }
__device__ inline unsigned bfpack(float a, float b) {     // mem order: [a, b]
    return (unsigned)f2bf(a) | ((unsigned)f2bf(b) << 16);
}

// ------- front: bf16 mirror of x, TRANSPOSED bf16 W (k-contiguous), cursors -
__global__ void front_kernel(const float* __restrict__ x,
                             const float* __restrict__ Wl1,
                             const float* __restrict__ Wr1,
                             const float* __restrict__ Wl2,
                             const float* __restrict__ Wr2,
                             unsigned short* __restrict__ xbf,
                             unsigned short* __restrict__ wbf_t,
                             int* __restrict__ binCursor) {
    const int tid = threadIdx.x;
    const int bid = blockIdx.x;
    if (bid < CVT_XBLOCKS) {
        int i = bid * 256 + tid;                  // float4 chunk of x
        if (i < NN * DD / 4) {
            float4 v = reinterpret_cast<const float4*>(x)[i];
            ushort4 u;
            u.x = f2bf(v.x); u.y = f2bf(v.y); u.z = f2bf(v.z); u.w = f2bf(v.w);
            reinterpret_cast<ushort4*>(xbf)[i] = u;
        }
    } else if (bid < CVT_XBLOCKS + 8) {
        // wbf_t[layer][col][k]: k<64 -> Wl[k][col], k>=64 -> Wr[k-64][col]
        int j = (bid - CVT_XBLOCKS) * 256 + tid;  // 0..2047 (uint4 index)
        int m   = j >> 10;                        // layer
        int col = (j >> 4) & 63;
        int kg  = j & 15;                         // k-group of 8
        const float* WlX = m ? Wl2 : Wl1;
        const float* WrX = m ? Wr2 : Wr1;
        unsigned short t8[8];
        #pragma unroll
        for (int t = 0; t < 8; ++t) {
            int k = kg * 8 + t;
            float v = (k < 64) ? WlX[k * 64 + col] : WrX[(k - 64) * 64 + col];
            t8[t] = f2bf(v);
        }
        uint4 u;
        u.x = (unsigned)t8[0] | ((unsigned)t8[1] << 16);
        u.y = (unsigned)t8[2] | ((unsigned)t8[3] << 16);
        u.z = (unsigned)t8[4] | ((unsigned)t8[5] << 16);
        u.w = (unsigned)t8[6] | ((unsigned)t8[7] << 16);
        reinterpret_cast<uint4*>(wbf_t)[j] = u;
    } else {
        for (int i = tid; i < NB32; i += 256) binCursor[i] = i * CAP32;
    }
}

// ------- scatter edges into fixed-capacity 32-node bin slots ---------------
// dst chunk staged once into LDS (read twice before: hist + placement).
__global__ void binscatter_kernel(const int* __restrict__ src, const int* __restrict__ dst,
                                  int* __restrict__ binCursor, unsigned* __restrict__ ebuf) {
    __shared__ int hist[NB32];
    __shared__ int base[NB32];
    __shared__ int dloc[PA_CHUNK];     // 12.5KB
    const int tid = threadIdx.x;
    const int e0 = blockIdx.x * PA_CHUNK;
    for (int i = tid; i < NB32; i += 256) hist[i] = 0;
    for (int i = tid; i < PA_CHUNK; i += 256) dloc[i] = dst[e0 + i];
    __syncthreads();
    for (int i = tid; i < PA_CHUNK; i += 256)
        atomicAdd(&hist[dloc[i] >> 5], 1);
    __syncthreads();
    for (int i = tid; i < NB32; i += 256) {
        int c = hist[i];
        base[i] = c ? atomicAdd(&binCursor[i], c) : 0;
        hist[i] = 0;               // reuse as local cursor
    }
    __syncthreads();
    for (int i = tid; i < PA_CHUNK; i += 256) {
        int d = dloc[i];
        int b = d >> 5;
        int off = atomicAdd(&hist[b], 1);
        ebuf[base[b] + off] = ((unsigned)(d & 31) << 16) | (unsigned)src[e0 + i];
    }
}

// ------- fused layer: [sort] + balanced gather -> bf16 A + MFMA GEMM -------
// One block per 32-node bin. Degree-descending perm assigns nodes to threads
// so each wave's 8 nodes have near-equal trip counts (kills max-of-8 skew).
__launch_bounds__(256, 5)
__global__ void fused_layer_kernel(const unsigned* __restrict__ ebuf,
                                   const int* __restrict__ binCursor,
                                   unsigned short* __restrict__ esrc,
                                   int* __restrict__ offs,
                                   const unsigned short* __restrict__ feat,
                                   const unsigned short* __restrict__ selfb,
                                   const unsigned short* __restrict__ Wbf, // [64][128] bf16
                                   const float* __restrict__ bias,
                                   float* __restrict__ outp,
                                   unsigned short* __restrict__ outbf,
                                   int relu, int sortMode) {
    __shared__ unsigned short eidx[CAP32];
    __shared__ int h32[32];
    __shared__ int loff[33];
    __shared__ unsigned char perm[32];
    __shared__ unsigned short Albs[32 * 128];   // 8KB  bf16 A tile
    __shared__ unsigned short Wlds[64 * 128];   // 16KB bf16 Wt; pre-stage: sort scratch
    const int tid = threadIdx.x;
    const int g = blockIdx.x;
    const int nbase = g * 32;
    const int e0 = g * CAP32;
    const int cnt = binCursor[g] - e0;
    char* Ab = reinterpret_cast<char*>(Albs);
    char* Wb = reinterpret_cast<char*>(Wlds);

    if (sortMode) {
        unsigned* scratch = reinterpret_cast<unsigned*>(Wlds);   // 4096 u32 >= CAP32
        for (int i = tid; i < cnt; i += 256) scratch[i] = ebuf[e0 + i];
        if (tid < 32) h32[tid] = 0;
        __syncthreads();
        for (int i = tid; i < cnt; i += 256)
            atomicAdd(&h32[(scratch[i] >> 16) & 31], 1);
        __syncthreads();
        if (tid == 0) {
            int run = 0;
            #pragma unroll
            for (int i = 0; i < 32; ++i) { loff[i] = run; run += h32[i]; }
            loff[32] = run;        // == cnt
        }
        __syncthreads();
        if (tid < 32) {
            offs[nbase + tid] = e0 + loff[tid];
            h32[tid] = loff[tid];  // reuse as cursor
        }
        // degree-descending rank permutation (loff final here)
        if (tid >= 64 && tid < 96) {
            int i = tid - 64;
            int deg = loff[i + 1] - loff[i];
            int r = 0;
            #pragma unroll 8
            for (int j = 0; j < 32; ++j) {
                int dj = loff[j + 1] - loff[j];
                r += (dj > deg) || (dj == deg && j < i);
            }
            perm[r] = (unsigned char)i;
        }
        __syncthreads();
        for (int i = tid; i < cnt; i += 256) {
            unsigned p = scratch[i];
            int n = (p >> 16) & 31;
            int pos = atomicAdd(&h32[n], 1);
            eidx[pos] = (unsigned short)(p & 0xFFFFu);
        }
        __syncthreads();           // scratch reads done; Wlds now reusable
        for (int i = tid; i < cnt; i += 256) esrc[e0 + i] = eidx[i];
    } else {
        if (tid < 32) loff[tid] = offs[nbase + tid] - e0;
        if (tid == 0) loff[32] = cnt;
        __syncthreads();
        for (int i = tid; i < cnt; i += 256) eidx[i] = esrc[e0 + i];
        if (tid >= 64 && tid < 96) {
            int i = tid - 64;
            int deg = loff[i + 1] - loff[i];
            int r = 0;
            #pragma unroll 8
            for (int j = 0; j < 32; ++j) {
                int dj = loff[j + 1] - loff[j];
                r += (dj > deg) || (dj == deg && j < i);
            }
            perm[r] = (unsigned char)i;
        }
        __syncthreads();
    }

    // ---- stage Wt into LDS (swizzled) [overlaps gather issue] ----
    #pragma unroll
    for (int i = 0; i < 4; ++i) {
        int idx = i * 256 + tid;            // 0..1023 uint4; col=idx>>4, kg=idx&15
        uint4 u = reinterpret_cast<const uint4*>(Wbf)[idx];
        int col = idx >> 4, kg = idx & 15;
        int byte = (col * 256 + kg * 16) ^ ((col & 7) << 4);
        *reinterpret_cast<uint4*>(Wb + byte) = u;
    }
    // ---- stage self rows into A[k=64..127] (straight bf16 copy) ----
    {
        int n  = tid >> 3;                  // 0..31
        int kq = tid & 7;                   // k-group 8..15
        int node = nbase + n;
        uint4 u = make_uint4(0u, 0u, 0u, 0u);
        if (node < NN)
            u = *reinterpret_cast<const uint4*>(selfb + (size_t)node * DD + kq * 8);
        int byte = (n * 256 + (8 + kq) * 16) ^ ((n & 7) << 4);
        *reinterpret_cast<uint4*>(Ab + byte) = u;
    }

    // ---- gather: 8 lanes/node, degree-balanced node assignment ----
    {
        const int nl = perm[tid >> 3];      // balanced local node
        const int q  = tid & 7;             // k-group 0..7 (elems q*8..q*8+7)
        const int qo = q << 3;
        const int le0 = loff[nl], le1 = loff[nl + 1];
        float a0 = 0.f, a1 = 0.f, a2 = 0.f, a3 = 0.f;
        float a4 = 0.f, a5 = 0.f, a6 = 0.f, a7 = 0.f;
        int e = le0;
        for (; e + 7 < le1; e += 8) {
            uint4 u0 = *reinterpret_cast<const uint4*>(feat + (size_t)eidx[e + 0] * DD + qo);
            uint4 u1 = *reinterpret_cast<const uint4*>(feat + (size_t)eidx[e + 1] * DD + qo);
            uint4 u2 = *reinterpret_cast<const uint4*>(feat + (size_t)eidx[e + 2] * DD + qo);
            uint4 u3 = *reinterpret_cast<const uint4*>(feat + (size_t)eidx[e + 3] * DD + qo);
            uint4 u4 = *reinterpret_cast<const uint4*>(feat + (size_t)eidx[e + 4] * DD + qo);
            uint4 u5 = *reinterpret_cast<const uint4*>(feat + (size_t)eidx[e + 5] * DD + qo);
            uint4 u6 = *reinterpret_cast<const uint4*>(feat + (size_t)eidx[e + 6] * DD + qo);
            uint4 u7 = *reinterpret_cast<const uint4*>(feat + (size_t)eidx[e + 7] * DD + qo);
            a0 += ((bflo(u0.x) + bflo(u1.x)) + (bflo(u2.x) + bflo(u3.x)))
                + ((bflo(u4.x) + bflo(u5.x)) + (bflo(u6.x) + bflo(u7.x)));
            a1 += ((bfhi(u0.x) + bfhi(u1.x)) + (bfhi(u2.x) + bfhi(u3.x)))
                + ((bfhi(u4.x) + bfhi(u5.x)) + (bfhi(u6.x) + bfhi(u7.x)));
            a2 += ((bflo(u0.y) + bflo(u1.y)) + (bflo(u2.y) + bflo(u3.y)))
                + ((bflo(u4.y) + bflo(u5.y)) + (bflo(u6.y) + bflo(u7.y)));
            a3 += ((bfhi(u0.y) + bfhi(u1.y)) + (bfhi(u2.y) + bfhi(u3.y)))
                + ((bfhi(u4.y) + bfhi(u5.y)) + (bfhi(u6.y) + bfhi(u7.y)));
            a4 += ((bflo(u0.z) + bflo(u1.z)) + (bflo(u2.z) + bflo(u3.z)))
                + ((bflo(u4.z) + bflo(u5.z)) + (bflo(u6.z) + bflo(u7.z)));
            a5 += ((bfhi(u0.z) + bfhi(u1.z)) + (bfhi(u2.z) + bfhi(u3.z)))
                + ((bfhi(u4.z) + bfhi(u5.z)) + (bfhi(u6.z) + bfhi(u7.z)));
            a6 += ((bflo(u0.w) + bflo(u1.w)) + (bflo(u2.w) + bflo(u3.w)))
                + ((bflo(u4.w) + bflo(u5.w)) + (bflo(u6.w) + bflo(u7.w)));
            a7 += ((bfhi(u0.w) + bfhi(u1.w)) + (bfhi(u2.w) + bfhi(u3.w)))
                + ((bfhi(u4.w) + bfhi(u5.w)) + (bfhi(u6.w) + bfhi(u7.w)));
        }
        for (; e + 1 < le1; e += 2) {
            uint4 u0 = *reinterpret_cast<const uint4*>(feat + (size_t)eidx[e + 0] * DD + qo);
            uint4 u1 = *reinterpret_cast<const uint4*>(feat + (size_t)eidx[e + 1] * DD + qo);
            a0 += bflo(u0.x) + bflo(u1.x); a1 += bfhi(u0.x) + bfhi(u1.x);
            a2 += bflo(u0.y) + bflo(u1.y); a3 += bfhi(u0.y) + bfhi(u1.y);
            a4 += bflo(u0.z) + bflo(u1.z); a5 += bfhi(u0.z) + bfhi(u1.z);
            a6 += bflo(u0.w) + bflo(u1.w); a7 += bfhi(u0.w) + bfhi(u1.w);
        }
        if (e < le1) {
            uint4 u0 = *reinterpret_cast<const uint4*>(feat + (size_t)eidx[e] * DD + qo);
            a0 += bflo(u0.x); a1 += bfhi(u0.x);
            a2 += bflo(u0.y); a3 += bfhi(u0.y);
            a4 += bflo(u0.z); a5 += bfhi(u0.z);
            a6 += bflo(u0.w); a7 += bfhi(u0.w);
        }
        float iv = (le1 > le0) ? (1.0f / (float)(le1 - le0)) : 0.0f;
        uint4 pk;
        pk.x = bfpack(a0 * iv, a1 * iv);
        pk.y = bfpack(a2 * iv, a3 * iv);
        pk.z = bfpack(a4 * iv, a5 * iv);
        pk.w = bfpack(a6 * iv, a7 * iv);
        int byte = (nl * 256 + q * 16) ^ ((nl & 7) << 4);
        *reinterpret_cast<uint4*>(Ab + byte) = pk;
    }
    __syncthreads();

    // ---- MFMA GEMM: out[32][64] = A[32][128] @ Wt^T + bias ----
    {
        const int lane = tid & 63;
        const int w = tid >> 6;             // wave 0..3
        const int mt = w & 1;               // M-tile (rows mt*16..+15)
        const int nt0 = (w >> 1) * 2;       // first N-tile
        const int lr = lane & 15;           // A-row / B-col within tile
        const int lg = lane >> 4;           // k-subgroup 0..3

        const int arow = mt * 16 + lr;
        const int c0 = nt0 * 16 + lr;
        const int c1 = c0 + 16;
        f32x4 acc0, acc1;
        {
            float b0 = bias[c0], b1 = bias[c1];
            #pragma unroll
            for (int r = 0; r < 4; ++r) { acc0[r] = b0; acc1[r] = b1; }
        }
        const int aswz = (arow & 7) << 4;
        const int b0swz = (c0 & 7) << 4;
        const int b1swz = (c1 & 7) << 4;
        #pragma unroll
        for (int ks = 0; ks < 4; ++ks) {
            int kg = ks * 4 + lg;           // k-group of 8 (k = kg*8)
            bf16x8 a = *reinterpret_cast<const bf16x8*>(
                Ab + ((arow * 256 + kg * 16) ^ aswz));
            bf16x8 b0 = *reinterpret_cast<const bf16x8*>(
                Wb + ((c0 * 256 + kg * 16) ^ b0swz));
            bf16x8 b1 = *reinterpret_cast<const bf16x8*>(
                Wb + ((c1 * 256 + kg * 16) ^ b1swz));
            acc0 = __builtin_amdgcn_mfma_f32_16x16x32_bf16(a, b0, acc0, 0, 0, 0);
            acc1 = __builtin_amdgcn_mfma_f32_16x16x32_bf16(a, b1, acc1, 0, 0, 0);
        }
        // epilogue: row = lg*4 + r (verified C/D mapping), col = lr
        #pragma unroll
        for (int r = 0; r < 4; ++r) {
            int node = nbase + mt * 16 + lg * 4 + r;
            if (node < NN) {
                float v0 = acc0[r], v1 = acc1[r];
                if (relu) { v0 = fmaxf(v0, 0.f); v1 = fmaxf(v1, 0.f); }
                if (outp) {
                    outp[(size_t)node * DD + c0] = v0;
                    outp[(size_t)node * DD + c1] = v1;
                }
                if (outbf) {
                    outbf[(size_t)node * DD + c0] = f2bf(v0);
                    outbf[(size_t)node * DD + c1] = f2bf(v1);
                }
            }
        }
    }
}

static inline size_t rup(size_t b) { return (b + 255) & ~(size_t)255; }

extern "C" void kernel_launch(void* const* d_in, const int* in_sizes, int n_in,
                              void* d_out, int out_size, void* d_ws, size_t ws_size,
                              hipStream_t stream) {
    const float* x   = (const float*)d_in[0];
    const int*   ei  = (const int*)d_in[1];
    const float* Wl1 = (const float*)d_in[2];
    const float* Wr1 = (const float*)d_in[3];
    const float* b1  = (const float*)d_in[4];
    const float* Wl2 = (const float*)d_in[5];
    const float* Wr2 = (const float*)d_in[6];
    const float* b2  = (const float*)d_in[7];
    float* out = (float*)d_out;

    const int* src = ei;        // edge_index[0]
    const int* dst = ei + EE;   // edge_index[1]

    // workspace layout (256B-aligned regions), ~14 MB
    char* p = (char*)d_ws;
    int* binCursor        = (int*)p;            p += rup((size_t)NB32 * 4);
    unsigned* ebuf        = (unsigned*)p;       p += rup((size_t)NB32 * CAP32 * 4);
    unsigned short* esrc  = (unsigned short*)p; p += rup((size_t)NB32 * CAP32 * 2);
    int* offs             = (int*)p;            p += rup((size_t)NB32 * 32 * 4);
    unsigned short* xbf   = (unsigned short*)p; p += rup((size_t)NN * DD * 2);
    unsigned short* hbf   = (unsigned short*)p; p += rup((size_t)NN * DD * 2);
    unsigned short* wbf_t = (unsigned short*)p; p += rup((size_t)2 * 64 * 128 * 2);

    // 4 launches total
    front_kernel<<<FRONT_BLOCKS, 256, 0, stream>>>(x, Wl1, Wr1, Wl2, Wr2,
                                                   xbf, wbf_t, binCursor);
    binscatter_kernel<<<PA_BLOCKS, 256, 0, stream>>>(src, dst, binCursor, ebuf);

    // layer 1: local sort + balanced gather(xbf) + MFMA GEMM -> hbf
    fused_layer_kernel<<<NB32, 256, 0, stream>>>(ebuf, binCursor, esrc, offs,
                                                 xbf, xbf, wbf_t, b1,
                                                 nullptr, hbf, 1, 1);
    // layer 2: balanced gather(hbf) + MFMA GEMM -> out
    fused_layer_kernel<<<NB32, 256, 0, stream>>>(ebuf, binCursor, esrc, offs,
                                                 hbf, hbf, wbf_t + 8192, b2,
                                                 out, nullptr, 0, 0);
}

// Round 25
// 68.514 us; speedup vs baseline: 1.0280x; 1.0250x over previous
//
#include <hip/hip_runtime.h>
#include <hip/hip_bf16.h>

#define NN 50000
#define EE 800000
#define DD 64
#define NB32 1563                  // ceil(NN / 32): 32-node bins
#define PA_BLOCKS 256
#define PA_CHUNK (EE / PA_BLOCKS)  // 3125
#define CAP32 768                  // capacity per 32-node bin (mean 512, 11 sigma)
#define CVT_XBLOCKS 3125
#define FRONT_BLOCKS (CVT_XBLOCKS + 8 + 1)

typedef short bf16x8 __attribute__((ext_vector_type(8)));   // 8 bf16 = 4 VGPR
typedef float f32x4 __attribute__((ext_vector_type(4)));

__device__ inline unsigned short f2bf(float f) {          // RNE float->bf16
    unsigned u = __float_as_uint(f);
    return (unsigned short)((u + 0x7FFF + ((u >> 16) & 1)) >> 16);
}
__device__ inline float bflo(unsigned u) { return __uint_as_float(u << 16); }
__device__ inline float bfhi(unsigned u) { return __uint_as_float(u & 0xFFFF0000u); }
__device__ inline unsigned bfpack(float a, float b) {     // mem order: [a, b]
    return (unsigned)f2bf(a) | ((unsigned)f2bf(b) << 16);
}

// ------- front: bf16 mirror of x, TRANSPOSED bf16 W (k-contiguous), cursors -
__global__ void front_kernel(const float* __restrict__ x,
                             const float* __restrict__ Wl1,
                             const float* __restrict__ Wr1,
                             const float* __restrict__ Wl2,
                             const float* __restrict__ Wr2,
                             unsigned short* __restrict__ xbf,
                             unsigned short* __restrict__ wbf_t,
                             int* __restrict__ binCursor) {
    const int tid = threadIdx.x;
    const int bid = blockIdx.x;
    if (bid < CVT_XBLOCKS) {
        int i = bid * 256 + tid;                  // float4 chunk of x
        if (i < NN * DD / 4) {
            float4 v = reinterpret_cast<const float4*>(x)[i];
            ushort4 u;
            u.x = f2bf(v.x); u.y = f2bf(v.y); u.z = f2bf(v.z); u.w = f2bf(v.w);
            reinterpret_cast<ushort4*>(xbf)[i] = u;
        }
    } else if (bid < CVT_XBLOCKS + 8) {
        // wbf_t[layer][col][k]: k<64 -> Wl[k][col], k>=64 -> Wr[k-64][col]
        int j = (bid - CVT_XBLOCKS) * 256 + tid;  // 0..2047 (uint4 index)
        int m   = j >> 10;                        // layer
        int col = (j >> 4) & 63;
        int kg  = j & 15;                         // k-group of 8
        const float* WlX = m ? Wl2 : Wl1;
        const float* WrX = m ? Wr2 : Wr1;
        unsigned short t8[8];
        #pragma unroll
        for (int t = 0; t < 8; ++t) {
            int k = kg * 8 + t;
            float v = (k < 64) ? WlX[k * 64 + col] : WrX[(k - 64) * 64 + col];
            t8[t] = f2bf(v);
        }
        uint4 u;
        u.x = (unsigned)t8[0] | ((unsigned)t8[1] << 16);
        u.y = (unsigned)t8[2] | ((unsigned)t8[3] << 16);
        u.z = (unsigned)t8[4] | ((unsigned)t8[5] << 16);
        u.w = (unsigned)t8[6] | ((unsigned)t8[7] << 16);
        reinterpret_cast<uint4*>(wbf_t)[j] = u;
    } else {
        for (int i = tid; i < NB32; i += 256) binCursor[i] = i * CAP32;
    }
}

// ------- scatter edges into fixed-capacity 32-node bin slots ---------------
__global__ void binscatter_kernel(const int* __restrict__ src, const int* __restrict__ dst,
                                  int* __restrict__ binCursor, unsigned* __restrict__ ebuf) {
    __shared__ int hist[NB32];
    __shared__ int base[NB32];
    const int tid = threadIdx.x;
    for (int i = tid; i < NB32; i += 256) hist[i] = 0;
    __syncthreads();
    const int e0 = blockIdx.x * PA_CHUNK;
    for (int e = e0 + tid; e < e0 + PA_CHUNK; e += 256)
        atomicAdd(&hist[dst[e] >> 5], 1);
    __syncthreads();
    for (int i = tid; i < NB32; i += 256) {
        int c = hist[i];
        base[i] = c ? atomicAdd(&binCursor[i], c) : 0;
        hist[i] = 0;               // reuse as local cursor
    }
    __syncthreads();
    for (int e = e0 + tid; e < e0 + PA_CHUNK; e += 256) {
        int d = dst[e];
        int b = d >> 5;
        int off = atomicAdd(&hist[b], 1);
        ebuf[base[b] + off] = ((unsigned)(d & 31) << 16) | (unsigned)src[e];
    }
}

// ------- fused layer: [sort] + gather -> bf16 A + MFMA K=128 GEMM ----------
// One block per 32-node bin. A = [agg | self] bf16 [32][128] (swizzled 16B
// slots); Wt = bf16 [64 cols][128 k] (k-contiguous). 4 waves, each: M-tile
// w&1, N-tiles (w>>1)*2,+1; 4 k-steps of mfma_f32_16x16x32_bf16. C/D map:
// col=lane&15, row=(lane>>4)*4+reg (verified layout).
__launch_bounds__(256, 5)
__global__ void fused_layer_kernel(const unsigned* __restrict__ ebuf,
                                   const int* __restrict__ binCursor,
                                   unsigned short* __restrict__ esrc,
                                   int* __restrict__ offs,
                                   const unsigned short* __restrict__ feat,
                                   const unsigned short* __restrict__ selfb,
                                   const unsigned short* __restrict__ Wbf, // [64][128] bf16
                                   const float* __restrict__ bias,
                                   float* __restrict__ outp,
                                   unsigned short* __restrict__ outbf,
                                   int relu, int sortMode) {
    __shared__ unsigned short eidx[CAP32];
    __shared__ int h32[32];
    __shared__ int loff[33];
    __shared__ unsigned short Albs[32 * 128];   // 8KB  bf16 A tile
    __shared__ unsigned short Wlds[64 * 128];   // 16KB bf16 Wt; pre-stage: sort scratch
    const int tid = threadIdx.x;
    const int g = blockIdx.x;
    const int nbase = g * 32;
    const int e0 = g * CAP32;
    const int cnt = binCursor[g] - e0;
    char* Ab = reinterpret_cast<char*>(Albs);
    char* Wb = reinterpret_cast<char*>(Wlds);

    if (sortMode) {
        unsigned* scratch = reinterpret_cast<unsigned*>(Wlds);   // 4096 u32 >= CAP32
        for (int i = tid; i < cnt; i += 256) scratch[i] = ebuf[e0 + i];
        if (tid < 32) h32[tid] = 0;
        __syncthreads();
        for (int i = tid; i < cnt; i += 256)
            atomicAdd(&h32[(scratch[i] >> 16) & 31], 1);
        __syncthreads();
        if (tid == 0) {
            int run = 0;
            #pragma unroll
            for (int i = 0; i < 32; ++i) { loff[i] = run; run += h32[i]; }
            loff[32] = run;        // == cnt
        }
        __syncthreads();
        if (tid < 32) {
            offs[nbase + tid] = e0 + loff[tid];
            h32[tid] = loff[tid];  // reuse as cursor
        }
        __syncthreads();
        for (int i = tid; i < cnt; i += 256) {
            unsigned p = scratch[i];
            int n = (p >> 16) & 31;
            int pos = atomicAdd(&h32[n], 1);
            eidx[pos] = (unsigned short)(p & 0xFFFFu);
        }
        __syncthreads();           // scratch reads done; Wlds now reusable
        for (int i = tid; i < cnt; i += 256) esrc[e0 + i] = eidx[i];
    } else {
        if (tid < 32) loff[tid] = offs[nbase + tid] - e0;
        if (tid == 0) loff[32] = cnt;
        __syncthreads();
        for (int i = tid; i < cnt; i += 256) eidx[i] = esrc[e0 + i];
        __syncthreads();
    }

    // ---- stage Wt into LDS (swizzled) [overlaps gather issue] ----
    #pragma unroll
    for (int i = 0; i < 4; ++i) {
        int idx = i * 256 + tid;            // 0..1023 uint4; col=idx>>4, kg=idx&15
        uint4 u = reinterpret_cast<const uint4*>(Wbf)[idx];
        int col = idx >> 4, kg = idx & 15;
        int byte = (col * 256 + kg * 16) ^ ((col & 7) << 4);
        *reinterpret_cast<uint4*>(Wb + byte) = u;
    }
    // ---- stage self rows into A[k=64..127] (straight bf16 copy) ----
    {
        int n  = tid >> 3;                  // 0..31
        int kq = tid & 7;                   // k-group 8..15
        int node = nbase + n;
        uint4 u = make_uint4(0u, 0u, 0u, 0u);
        if (node < NN)
            u = *reinterpret_cast<const uint4*>(selfb + (size_t)node * DD + kq * 8);
        int byte = (n * 256 + (8 + kq) * 16) ^ ((n & 7) << 4);
        *reinterpret_cast<uint4*>(Ab + byte) = u;
    }

    // ---- gather: 8 lanes/node, 1 node/thread, 8-deep unroll -> A[k=0..63] --
    {
        const int nl = tid >> 3;            // 0..31 local node
        const int q  = tid & 7;             // k-group 0..7 (elems q*8..q*8+7)
        const int qo = q << 3;
        const int le0 = loff[nl], le1 = loff[nl + 1];
        float a0 = 0.f, a1 = 0.f, a2 = 0.f, a3 = 0.f;
        float a4 = 0.f, a5 = 0.f, a6 = 0.f, a7 = 0.f;
        int e = le0;
        for (; e + 7 < le1; e += 8) {
            uint4 u0 = *reinterpret_cast<const uint4*>(feat + (size_t)eidx[e + 0] * DD + qo);
            uint4 u1 = *reinterpret_cast<const uint4*>(feat + (size_t)eidx[e + 1] * DD + qo);
            uint4 u2 = *reinterpret_cast<const uint4*>(feat + (size_t)eidx[e + 2] * DD + qo);
            uint4 u3 = *reinterpret_cast<const uint4*>(feat + (size_t)eidx[e + 3] * DD + qo);
            uint4 u4 = *reinterpret_cast<const uint4*>(feat + (size_t)eidx[e + 4] * DD + qo);
            uint4 u5 = *reinterpret_cast<const uint4*>(feat + (size_t)eidx[e + 5] * DD + qo);
            uint4 u6 = *reinterpret_cast<const uint4*>(feat + (size_t)eidx[e + 6] * DD + qo);
            uint4 u7 = *reinterpret_cast<const uint4*>(feat + (size_t)eidx[e + 7] * DD + qo);
            a0 += ((bflo(u0.x) + bflo(u1.x)) + (bflo(u2.x) + bflo(u3.x)))
                + ((bflo(u4.x) + bflo(u5.x)) + (bflo(u6.x) + bflo(u7.x)));
            a1 += ((bfhi(u0.x) + bfhi(u1.x)) + (bfhi(u2.x) + bfhi(u3.x)))
                + ((bfhi(u4.x) + bfhi(u5.x)) + (bfhi(u6.x) + bfhi(u7.x)));
            a2 += ((bflo(u0.y) + bflo(u1.y)) + (bflo(u2.y) + bflo(u3.y)))
                + ((bflo(u4.y) + bflo(u5.y)) + (bflo(u6.y) + bflo(u7.y)));
            a3 += ((bfhi(u0.y) + bfhi(u1.y)) + (bfhi(u2.y) + bfhi(u3.y)))
                + ((bfhi(u4.y) + bfhi(u5.y)) + (bfhi(u6.y) + bfhi(u7.y)));
            a4 += ((bflo(u0.z) + bflo(u1.z)) + (bflo(u2.z) + bflo(u3.z)))
                + ((bflo(u4.z) + bflo(u5.z)) + (bflo(u6.z) + bflo(u7.z)));
            a5 += ((bfhi(u0.z) + bfhi(u1.z)) + (bfhi(u2.z) + bfhi(u3.z)))
                + ((bfhi(u4.z) + bfhi(u5.z)) + (bfhi(u6.z) + bfhi(u7.z)));
            a6 += ((bflo(u0.w) + bflo(u1.w)) + (bflo(u2.w) + bflo(u3.w)))
                + ((bflo(u4.w) + bflo(u5.w)) + (bflo(u6.w) + bflo(u7.w)));
            a7 += ((bfhi(u0.w) + bfhi(u1.w)) + (bfhi(u2.w) + bfhi(u3.w)))
                + ((bfhi(u4.w) + bfhi(u5.w)) + (bfhi(u6.w) + bfhi(u7.w)));
        }
        for (; e + 1 < le1; e += 2) {
            uint4 u0 = *reinterpret_cast<const uint4*>(feat + (size_t)eidx[e + 0] * DD + qo);
            uint4 u1 = *reinterpret_cast<const uint4*>(feat + (size_t)eidx[e + 1] * DD + qo);
            a0 += bflo(u0.x) + bflo(u1.x); a1 += bfhi(u0.x) + bfhi(u1.x);
            a2 += bflo(u0.y) + bflo(u1.y); a3 += bfhi(u0.y) + bfhi(u1.y);
            a4 += bflo(u0.z) + bflo(u1.z); a5 += bfhi(u0.z) + bfhi(u1.z);
            a6 += bflo(u0.w) + bflo(u1.w); a7 += bfhi(u0.w) + bfhi(u1.w);
        }
        if (e < le1) {
            uint4 u0 = *reinterpret_cast<const uint4*>(feat + (size_t)eidx[e] * DD + qo);
            a0 += bflo(u0.x); a1 += bfhi(u0.x);
            a2 += bflo(u0.y); a3 += bfhi(u0.y);
            a4 += bflo(u0.z); a5 += bfhi(u0.z);
            a6 += bflo(u0.w); a7 += bfhi(u0.w);
        }
        float iv = (le1 > le0) ? (1.0f / (float)(le1 - le0)) : 0.0f;
        uint4 pk;
        pk.x = bfpack(a0 * iv, a1 * iv);
        pk.y = bfpack(a2 * iv, a3 * iv);
        pk.z = bfpack(a4 * iv, a5 * iv);
        pk.w = bfpack(a6 * iv, a7 * iv);
        int byte = (nl * 256 + q * 16) ^ ((nl & 7) << 4);
        *reinterpret_cast<uint4*>(Ab + byte) = pk;
    }
    __syncthreads();

    // ---- MFMA GEMM: out[32][64] = A[32][128] @ Wt^T + bias ----
    {
        const int lane = tid & 63;
        const int w = tid >> 6;             // wave 0..3
        const int mt = w & 1;               // M-tile (rows mt*16..+15)
        const int nt0 = (w >> 1) * 2;       // first N-tile
        const int lr = lane & 15;           // A-row / B-col within tile
        const int lg = lane >> 4;           // k-subgroup 0..3

        const int arow = mt * 16 + lr;
        const int c0 = nt0 * 16 + lr;
        const int c1 = c0 + 16;
        f32x4 acc0, acc1;
        {
            float b0 = bias[c0], b1 = bias[c1];
            #pragma unroll
            for (int r = 0; r < 4; ++r) { acc0[r] = b0; acc1[r] = b1; }
        }
        const int aswz = (arow & 7) << 4;
        const int b0swz = (c0 & 7) << 4;
        const int b1swz = (c1 & 7) << 4;
        #pragma unroll
        for (int ks = 0; ks < 4; ++ks) {
            int kg = ks * 4 + lg;           // k-group of 8 (k = kg*8)
            bf16x8 a = *reinterpret_cast<const bf16x8*>(
                Ab + ((arow * 256 + kg * 16) ^ aswz));
            bf16x8 b0 = *reinterpret_cast<const bf16x8*>(
                Wb + ((c0 * 256 + kg * 16) ^ b0swz));
            bf16x8 b1 = *reinterpret_cast<const bf16x8*>(
                Wb + ((c1 * 256 + kg * 16) ^ b1swz));
            acc0 = __builtin_amdgcn_mfma_f32_16x16x32_bf16(a, b0, acc0, 0, 0, 0);
            acc1 = __builtin_amdgcn_mfma_f32_16x16x32_bf16(a, b1, acc1, 0, 0, 0);
        }
        // epilogue: row = lg*4 + r (verified C/D mapping), col = lr
        #pragma unroll
        for (int r = 0; r < 4; ++r) {
            int node = nbase + mt * 16 + lg * 4 + r;
            if (node < NN) {
                float v0 = acc0[r], v1 = acc1[r];
                if (relu) { v0 = fmaxf(v0, 0.f); v1 = fmaxf(v1, 0.f); }
                if (outp) {
                    outp[(size_t)node * DD + c0] = v0;
                    outp[(size_t)node * DD + c1] = v1;
                }
                if (outbf) {
                    outbf[(size_t)node * DD + c0] = f2bf(v0);
                    outbf[(size_t)node * DD + c1] = f2bf(v1);
                }
            }
        }
    }
}

static inline size_t rup(size_t b) { return (b + 255) & ~(size_t)255; }

extern "C" void kernel_launch(void* const* d_in, const int* in_sizes, int n_in,
                              void* d_out, int out_size, void* d_ws, size_t ws_size,
                              hipStream_t stream) {
    const float* x   = (const float*)d_in[0];
    const int*   ei  = (const int*)d_in[1];
    const float* Wl1 = (const float*)d_in[2];
    const float* Wr1 = (const float*)d_in[3];
    const float* b1  = (const float*)d_in[4];
    const float* Wl2 = (const float*)d_in[5];
    const float* Wr2 = (const float*)d_in[6];
    const float* b2  = (const float*)d_in[7];
    float* out = (float*)d_out;

    const int* src = ei;        // edge_index[0]
    const int* dst = ei + EE;   // edge_index[1]

    // workspace layout (256B-aligned regions), ~14 MB
    char* p = (char*)d_ws;
    int* binCursor        = (int*)p;            p += rup((size_t)NB32 * 4);
    unsigned* ebuf        = (unsigned*)p;       p += rup((size_t)NB32 * CAP32 * 4);
    unsigned short* esrc  = (unsigned short*)p; p += rup((size_t)NB32 * CAP32 * 2);
    int* offs             = (int*)p;            p += rup((size_t)NB32 * 32 * 4);
    unsigned short* xbf   = (unsigned short*)p; p += rup((size_t)NN * DD * 2);
    unsigned short* hbf   = (unsigned short*)p; p += rup((size_t)NN * DD * 2);
    unsigned short* wbf_t = (unsigned short*)p; p += rup((size_t)2 * 64 * 128 * 2);

    // 4 launches total
    front_kernel<<<FRONT_BLOCKS, 256, 0, stream>>>(x, Wl1, Wr1, Wl2, Wr2,
                                                   xbf, wbf_t, binCursor);
    binscatter_kernel<<<PA_BLOCKS, 256, 0, stream>>>(src, dst, binCursor, ebuf);

    // layer 1: local sort + gather(xbf) + MFMA GEMM -> hbf (emits esrc/offs)
    fused_layer_kernel<<<NB32, 256, 0, stream>>>(ebuf, binCursor, esrc, offs,
                                                 xbf, xbf, wbf_t, b1,
                                                 nullptr, hbf, 1, 1);
    // layer 2: gather(hbf) + MFMA GEMM -> out
    fused_layer_kernel<<<NB32, 256, 0, stream>>>(ebuf, binCursor, esrc, offs,
                                                 hbf, hbf, wbf_t + 8192, b2,
                                                 out, nullptr, 0, 0);
}